// Round 10
// baseline (294.105 us; speedup 1.0000x reference)
//
#include <hip/hip_runtime.h>
#include <hip/hip_cooperative_groups.h>

namespace cg = cooperative_groups;

#define D 1024
#define B 32
#define NI 1024
#define PP 1000
#define R 3
#define SPLITS 8        // split-K factor for weight GEMMs (K chunk = 128)
#define VS 8            // p-split factor for v_agg (128 padded p each)
#define BK 32
#define KT (D / SPLITS / BK)   // k-tiles per split
#define PAD 34          // row pad (floats): b64 reads land 2-way-conflict only (free)

typedef float f32x4_t __attribute__((ext_vector_type(4)));

__device__ __forceinline__ void nt_store4(float* p, float4 v) {
    f32x4_t x = {v.x, v.y, v.z, v.w};
    __builtin_nontemporal_store(x, (f32x4_t*)p);
}

__device__ __forceinline__ float wred(float x) {
    #pragma unroll
    for (int off = 32; off; off >>= 1) x += __shfl_xor(x, off, 64);
    return x;
}
__device__ __forceinline__ float wmax(float x) {
    #pragma unroll
    for (int off = 32; off; off >>= 1) x = fmaxf(x, __shfl_xor(x, off, 64));
    return x;
}

// ---------------------------------------------------------------------------
// Tiled GEMM core (LDS passed in): C[m,b] = sum_k A[m,k]*X[b,k], K in [kc0, kc0+128)
// ---------------------------------------------------------------------------
template<int NXS>
__device__ __forceinline__ void gemm_core_l(
        const float* __restrict__ A, int mbase, int Mrows,
        const float* __restrict__ Xb, int xrstride, size_t xss,
        int kc0, float acc[4][4], float (*Ws)[PAD], float (*Xs)[PAD]) {
    const int t = threadIdx.x;
    const int ty = t >> 3, tx = t & 7;
    const int m0 = 4 * ty, b0 = 4 * tx;
    const int lrow = t >> 3, lq = t & 7;

    #pragma unroll
    for (int i = 0; i < 4; ++i)
        #pragma unroll
        for (int j = 0; j < 4; ++j) acc[i][j] = 0.f;

    for (int kt = 0; kt < KT; ++kt) {
        const int kc = kc0 + kt * BK;
        #pragma unroll
        for (int rr = 0; rr < 4; ++rr) {
            const int row = lrow + 32 * rr;
            float4 v = make_float4(0.f, 0.f, 0.f, 0.f);
            if (mbase + row < Mrows)
                v = *(const float4*)(A + (size_t)(mbase + row) * D + kc + 4 * lq);
            *(float2*)&Ws[row][4 * lq]     = make_float2(v.x, v.y);
            *(float2*)&Ws[row][4 * lq + 2] = make_float2(v.z, v.w);
        }
        {
            const float* xp = Xb + (size_t)lrow * xrstride + kc + 4 * lq;
            float4 v = *(const float4*)xp;
            #pragma unroll
            for (int s = 1; s < NXS; ++s) {
                float4 w = *(const float4*)(xp + (size_t)s * xss);
                v.x += w.x; v.y += w.y; v.z += w.z; v.w += w.w;
            }
            *(float2*)&Xs[lrow][4 * lq]     = make_float2(v.x, v.y);
            *(float2*)&Xs[lrow][4 * lq + 2] = make_float2(v.z, v.w);
        }
        __syncthreads();
        #pragma unroll
        for (int kp = 0; kp < 16; ++kp) {
            float2 wv[4], xv[4];
            #pragma unroll
            for (int i = 0; i < 4; ++i) wv[i] = *(const float2*)&Ws[m0 + i][2 * kp];
            #pragma unroll
            for (int j = 0; j < 4; ++j) xv[j] = *(const float2*)&Xs[b0 + j][2 * kp];
            #pragma unroll
            for (int i = 0; i < 4; ++i)
                #pragma unroll
                for (int j = 0; j < 4; ++j) {
                    acc[i][j] += wv[i].x * xv[j].x;
                    acc[i][j] += wv[i].y * xv[j].y;
                }
        }
        __syncthreads();
    }
}

// ---------------------------------------------------------------------------
// chain_all: the entire small chain as one cooperative kernel, 192 blocks.
// Stages separated by grid.sync(); LDS aliased per stage.
// ---------------------------------------------------------------------------
__global__ __launch_bounds__(256) void chain_all(
        const float* __restrict__ fc, const float* __restrict__ pool,
        const float* __restrict__ Wagg, const float* __restrict__ Wq,
        const float* __restrict__ Wk, const float* __restrict__ Wv,
        const float* __restrict__ bq, const float* __restrict__ bk,
        const float* __restrict__ bv, const float* __restrict__ Wc,
        const float* __restrict__ bc, const float* __restrict__ Wg,
        const float* __restrict__ bg,
        float* __restrict__ qallp, float* __restrict__ scp,
        float* __restrict__ wbar, float* __restrict__ vaggp,
        float* __restrict__ qkvp, float* __restrict__ ub,
        float* __restrict__ vdp, float* __restrict__ vdiff,
        float* __restrict__ cb) {
    cg::grid_group grid = cg::this_grid();
    const int bid = blockIdx.x;
    const int t = threadIdx.x;
    __shared__ float lds_raw[160 * PAD];    // 5440 floats, aliased per stage
    __shared__ float red8[8];
    float (*Ws)[PAD] = (float(*)[PAD])lds_raw;
    float (*Xs)[PAD] = (float(*)[PAD])&lds_raw[128 * PAD];
    const int ty = t >> 3, tx = t & 7;

    // ---- S1: qall partials (192 = 24 mb x 8 s) ----
    {
        const int mb = bid / SPLITS, s = bid % SPLITS;
        float acc[4][4];
        gemm_core_l<1>(Wagg, mb * 128, R * D, fc, D, 0, s * 128, acc, Ws, Xs);
        const int m = mb * 128 + 4 * ty;
        #pragma unroll
        for (int j = 0; j < 4; ++j) {
            float* cp = qallp + ((size_t)(s * B) + 4 * tx + j) * (R * D) + m;
            *(float4*)cp = make_float4(acc[0][j], acc[1][j], acc[2][j], acc[3][j]);
        }
    }
    grid.sync();

    // ---- S2: score partials (192 = 3 r x 8 s x 8 mb) ----
    {
        const int r = bid / 64, rem = bid % 64;
        const int s = rem >> 3, mb = rem & 7;
        float acc[4][4];
        gemm_core_l<SPLITS>(pool, mb * 128, PP, qallp + r * D, R * D,
                            (size_t)B * R * D, s * 128, acc, Ws, Xs);
        const int m = mb * 128 + 4 * ty;
        if (m < PP) {
            #pragma unroll
            for (int j = 0; j < 4; ++j) {
                float* cp = scp + ((size_t)((s * R + r) * B) + 4 * tx + j) * D + m;
                *(float4*)cp = make_float4(acc[0][j], acc[1][j], acc[2][j], acc[3][j]);
            }
        }
    }
    grid.sync();

    // ---- S3: softmax + wbar (32 blocks) ----
    if (bid < B) {
        const int b = bid;
        const int w = t >> 6, lane = t & 63;
        float wb[4] = {0.f, 0.f, 0.f, 0.f};
        for (int r = 0; r < R; ++r) {
            float v[4];
            float mx = -1e30f;
            #pragma unroll
            for (int i = 0; i < 4; ++i) {
                const int p = t + 256 * i;
                float x = -1e30f;
                if (p < PP) {
                    x = 0.f;
                    #pragma unroll
                    for (int s = 0; s < SPLITS; ++s)
                        x += scp[((size_t)((s * R + r) * B) + b) * D + p];
                    x *= 0.03125f;
                }
                v[i] = x;
                mx = fmaxf(mx, x);
            }
            mx = wmax(mx);
            if (lane == 0) red8[w] = mx;
            __syncthreads();
            mx = fmaxf(fmaxf(red8[0], red8[1]), fmaxf(red8[2], red8[3]));
            float e[4], sum = 0.f;
            #pragma unroll
            for (int i = 0; i < 4; ++i) {
                const int p = t + 256 * i;
                e[i] = (p < PP) ? __expf(v[i] - mx) : 0.f;
                sum += e[i];
            }
            sum = wred(sum);
            if (lane == 0) red8[4 + w] = sum;
            __syncthreads();
            const float inv = 1.f / (red8[4] + red8[5] + red8[6] + red8[7]);
            #pragma unroll
            for (int i = 0; i < 4; ++i) wb[i] += e[i] * inv;
            __syncthreads();
        }
        #pragma unroll
        for (int i = 0; i < 4; ++i)
            wbar[(size_t)b * 1024 + t + 256 * i] = wb[i] * (1.f / 3.f);
    }
    grid.sync();

    // ---- S4: v_agg partials (64) + q partials (64) ----
    if (bid < 64) {
        // k4: db = bid & 7, ps = bid >> 3
        const int db = bid & 7, ps = bid >> 3;
        float (*Ps)[132] = (float(*)[132])lds_raw;
        float (*Wbt)[36] = (float(*)[36])&lds_raw[32 * 132];
        float acc[4][4];
        #pragma unroll
        for (int i = 0; i < 4; ++i)
            #pragma unroll
            for (int j = 0; j < 4; ++j) acc[i][j] = 0.f;
        for (int pt = 0; pt < 4; ++pt) {
            const int p0 = ps * 128 + pt * 32;
            {
                const int prow = t >> 5, qc = t & 31;
                #pragma unroll
                for (int rr = 0; rr < 4; ++rr) {
                    const int pr = prow + 8 * rr;
                    float4 v = make_float4(0.f, 0.f, 0.f, 0.f);
                    if (p0 + pr < PP)
                        v = *(const float4*)(pool + (size_t)(p0 + pr) * D + db * 128 + 4 * qc);
                    *(float4*)&Ps[pr][4 * qc] = v;
                }
            }
            {
                const int bb = t >> 3, q = t & 7;
                float4 v = *(const float4*)(wbar + (size_t)bb * 1024 + p0 + 4 * q);
                Wbt[4 * q + 0][bb] = v.x; Wbt[4 * q + 1][bb] = v.y;
                Wbt[4 * q + 2][bb] = v.z; Wbt[4 * q + 3][bb] = v.w;
            }
            __syncthreads();
            #pragma unroll
            for (int pg = 0; pg < 8; ++pg) {
                #pragma unroll
                for (int pp = 0; pp < 4; ++pp) {
                    const int p = 4 * pg + pp;
                    float4 xv = *(const float4*)&Ps[p][4 * ty];
                    float4 wv = *(const float4*)&Wbt[p][4 * tx];
                    const float xsv[4] = {xv.x, xv.y, xv.z, xv.w};
                    const float wsv[4] = {wv.x, wv.y, wv.z, wv.w};
                    #pragma unroll
                    for (int i = 0; i < 4; ++i)
                        #pragma unroll
                        for (int j = 0; j < 4; ++j)
                            acc[i][j] += xsv[i] * wsv[j];
                }
            }
            __syncthreads();
        }
        const int dbase = db * 128 + 4 * ty;
        #pragma unroll
        for (int j = 0; j < 4; ++j) {
            float* op = vaggp + ((size_t)ps * B + 4 * tx + j) * D + dbase;
            *(float4*)op = make_float4(acc[0][j], acc[1][j], acc[2][j], acc[3][j]);
        }
    } else if (bid < 128) {
        // q partials: i = bid-64 -> mb = i&7, s = i>>3 ; kind 0 of qkvp
        const int i0 = bid - 64;
        const int mb = i0 & 7, s = i0 >> 3;
        float acc[4][4];
        gemm_core_l<1>(Wq, mb * 128, D, fc, D, 0, s * 128, acc, Ws, Xs);
        const int m = mb * 128 + 4 * ty;
        #pragma unroll
        for (int j = 0; j < 4; ++j) {
            float* cp = qkvp + ((size_t)((s * R + 0) * B) + 4 * tx + j) * D + m;
            *(float4*)cp = make_float4(acc[0][j], acc[1][j], acc[2][j], acc[3][j]);
        }
    }
    grid.sync();

    // ---- S5: k/v partials (128 = 2 z x 8 s x 8 mb), X = sum of VS vagg partials ----
    if (bid < 128) {
        const int z = bid >> 6, rem = bid & 63;
        const int s = rem >> 3, mb = rem & 7;
        float acc[4][4];
        gemm_core_l<VS>((z == 0) ? Wk : Wv, mb * 128, D, vaggp, D,
                        (size_t)B * D, s * 128, acc, Ws, Xs);
        const int m = mb * 128 + 4 * ty;
        #pragma unroll
        for (int j = 0; j < 4; ++j) {
            float* cp = qkvp + ((size_t)((s * R + z + 1) * B) + 4 * tx + j) * D + m;
            *(float4*)cp = make_float4(acc[0][j], acc[1][j], acc[2][j], acc[3][j]);
        }
    }
    grid.sync();

    // ---- S6: u = vhat - sigmoid(sim)*v (32 blocks) ----
    if (bid < B) {
        const int b = bid;
        const int w = t >> 6, lane = t & 63;
        const int d = 4 * t;
        float4 qv = *(const float4*)(bq + d);
        float4 kv = *(const float4*)(bk + d);
        #pragma unroll
        for (int s = 0; s < SPLITS; ++s) {
            float4 a = *(const float4*)(qkvp + ((size_t)((s * R + 0) * B) + b) * D + d);
            float4 c = *(const float4*)(qkvp + ((size_t)((s * R + 1) * B) + b) * D + d);
            qv.x += a.x; qv.y += a.y; qv.z += a.z; qv.w += a.w;
            kv.x += c.x; kv.y += c.y; kv.z += c.z; kv.w += c.w;
        }
        float local = qv.x * kv.x + qv.y * kv.y + qv.z * kv.z + qv.w * kv.w;
        local = wred(local);
        if (lane == 0) red8[w] = local;
        __syncthreads();
        const float sim = (red8[0] + red8[1] + red8[2] + red8[3]) * 0.03125f;
        const float sig = 1.f / (1.f + __expf(-sim));
        float4 vv = *(const float4*)(bv + d);
        #pragma unroll
        for (int s = 0; s < SPLITS; ++s) {
            float4 c = *(const float4*)(qkvp + ((size_t)((s * R + 2) * B) + b) * D + d);
            vv.x += c.x; vv.y += c.y; vv.z += c.z; vv.w += c.w;
        }
        const float4 vh = *(const float4*)(fc + (size_t)b * D + d);
        float4 o;
        o.x = vh.x - sig * vv.x; o.y = vh.y - sig * vv.y;
        o.z = vh.z - sig * vv.z; o.w = vh.w - sig * vv.w;
        *(float4*)(ub + (size_t)b * D + d) = o;
    }
    grid.sync();

    // ---- S7: v_diff pre-act partials (64 = 8 s x 8 mb) ----
    if (bid < 64) {
        const int s = bid >> 3, mb = bid & 7;
        float acc[4][4];
        gemm_core_l<1>(Wc, mb * 128, D, ub, D, 0, s * 128, acc, Ws, Xs);
        const int m = mb * 128 + 4 * ty;
        #pragma unroll
        for (int j = 0; j < 4; ++j) {
            float* cp = vdp + ((size_t)(s * B) + 4 * tx + j) * D + m;
            *(float4*)cp = make_float4(acc[0][j], acc[1][j], acc[2][j], acc[3][j]);
        }
    }
    grid.sync();

    // ---- S8: vdiff = relu(sum partials + bc); cb = vdiff.Wg2 + bg (32 blocks) ----
    if (bid < B) {
        const int b = bid;
        const int w = t >> 6, lane = t & 63;
        const int d = 4 * t;
        float4 a = *(const float4*)(bc + d);
        #pragma unroll
        for (int s = 0; s < SPLITS; ++s) {
            float4 c = *(const float4*)(vdp + ((size_t)(s * B) + b) * D + d);
            a.x += c.x; a.y += c.y; a.z += c.z; a.w += c.w;
        }
        a.x = fmaxf(a.x, 0.f); a.y = fmaxf(a.y, 0.f);
        a.z = fmaxf(a.z, 0.f); a.w = fmaxf(a.w, 0.f);
        *(float4*)(vdiff + (size_t)b * D + d) = a;
        const float4 g2 = *(const float4*)(Wg + D + d);
        float local = a.x * g2.x + a.y * g2.y + a.z * g2.z + a.w * g2.w;
        local = wred(local);
        if (lane == 0) red8[w] = local;
        __syncthreads();
        if (t == 0) cb[b] = red8[0] + red8[1] + red8[2] + red8[3] + bg[0];
    }
}

// K9: out[b,n,d] = att + rs * sigmoid(att[b,n,:].Wg1 + cb[b]) * vdiff[b,d]
// (round-9 persistent variant, 76us — best of 6 structures tried)
__global__ __launch_bounds__(256, 2) void k9_main(const float* __restrict__ att,
        const float* __restrict__ Wg, const float* __restrict__ cb,
        const float* __restrict__ vdiff, const float* __restrict__ rs_p,
        float* __restrict__ out) {
    __shared__ float vds[1024];
    const int t = threadIdx.x;
    const int b = blockIdx.x >> 5;          // 32 blocks per batch
    *(float4*)&vds[4 * t] = *(const float4*)(vdiff + (size_t)b * D + 4 * t);
    __syncthreads();
    const int w = t >> 6, lane = t & 63;
    float4 g[4];
    #pragma unroll
    for (int kk = 0; kk < 4; ++kk)
        g[kk] = *(const float4*)(Wg + 4 * lane + 256 * kk);
    const float rsv = rs_p[0];
    const float cbb = cb[b];
    const size_t row0 = (size_t)b * NI + (size_t)(blockIdx.x & 31) * 32 + w * 8;
    const float* ap = att + row0 * D;
    float* op = out + row0 * D;

    float4 cur[8], nxt[8];
    #pragma unroll
    for (int q = 0; q < 8; ++q)
        cur[q] = *(const float4*)(ap + (size_t)(q >> 2) * D + 4 * lane + 256 * (q & 3));

    #pragma unroll
    for (int it = 0; it < 4; ++it) {
        if (it < 3) {
            const float* apn = ap + (size_t)(2 * it + 2) * D;
            #pragma unroll
            for (int q = 0; q < 8; ++q)
                nxt[q] = *(const float4*)(apn + (size_t)(q >> 2) * D + 4 * lane + 256 * (q & 3));
        }
        float acc0 = 0.f, acc1 = 0.f;
        #pragma unroll
        for (int kk = 0; kk < 4; ++kk) {
            acc0 += cur[kk].x * g[kk].x + cur[kk].y * g[kk].y +
                    cur[kk].z * g[kk].z + cur[kk].w * g[kk].w;
            acc1 += cur[4 + kk].x * g[kk].x + cur[4 + kk].y * g[kk].y +
                    cur[4 + kk].z * g[kk].z + cur[4 + kk].w * g[kk].w;
        }
        #pragma unroll
        for (int off = 32; off; off >>= 1) {
            acc0 += __shfl_xor(acc0, off, 64);
            acc1 += __shfl_xor(acc1, off, 64);
        }
        const float grs0 = rsv / (1.f + __expf(-(acc0 + cbb)));
        const float grs1 = rsv / (1.f + __expf(-(acc1 + cbb)));
        float* op0 = op + (size_t)(2 * it) * D;
        #pragma unroll
        for (int kk = 0; kk < 4; ++kk) {
            const int col = 4 * lane + 256 * kk;
            const float4 vd = *(const float4*)&vds[col];
            float4 o0, o1;
            o0.x = cur[kk].x + grs0 * vd.x; o0.y = cur[kk].y + grs0 * vd.y;
            o0.z = cur[kk].z + grs0 * vd.z; o0.w = cur[kk].w + grs0 * vd.w;
            o1.x = cur[4 + kk].x + grs1 * vd.x; o1.y = cur[4 + kk].y + grs1 * vd.y;
            o1.z = cur[4 + kk].z + grs1 * vd.z; o1.w = cur[4 + kk].w + grs1 * vd.w;
            nt_store4(op0 + col, o0);
            nt_store4(op0 + D + col, o1);
        }
        if (it < 3) {
            #pragma unroll
            for (int q = 0; q < 8; ++q) cur[q] = nxt[q];
        }
    }
}

extern "C" void kernel_launch(void* const* d_in, const int* in_sizes, int n_in,
                              void* d_out, int out_size, void* d_ws, size_t ws_size,
                              hipStream_t stream) {
    const float* att  = (const float*)d_in[0];
    const float* fc   = (const float*)d_in[1];
    const float* pool = (const float*)d_in[2];
    const float* Wagg = (const float*)d_in[3];
    const float* Wq   = (const float*)d_in[4];
    const float* bq   = (const float*)d_in[5];
    const float* Wk   = (const float*)d_in[6];
    const float* bk   = (const float*)d_in[7];
    const float* Wv   = (const float*)d_in[8];
    const float* bv   = (const float*)d_in[9];
    const float* Wc   = (const float*)d_in[10];
    const float* bc   = (const float*)d_in[11];
    const float* Wg   = (const float*)d_in[12];
    const float* bg   = (const float*)d_in[13];
    const float* rs   = (const float*)d_in[14];
    float* out = (float*)d_out;

    float* ws = (float*)d_ws;
    float* qallp = ws;                                  // SPLITS*B*R*D
    float* scp   = qallp + (size_t)SPLITS * B * R * D;  // SPLITS*R*B*D
    float* wbar  = scp + (size_t)SPLITS * R * B * D;    // B*1024
    float* vaggp = wbar + (size_t)B * 1024;             // VS*B*D
    float* qkvp  = vaggp + (size_t)VS * B * D;          // SPLITS*R*B*D
    float* ub    = qkvp + (size_t)SPLITS * R * B * D;   // B*D
    float* vdp   = ub + (size_t)B * D;                  // SPLITS*B*D
    float* vdiff = vdp + (size_t)SPLITS * B * D;        // B*D
    float* cbuf  = vdiff + (size_t)B * D;               // B

    void* args[] = {
        (void*)&fc, (void*)&pool, (void*)&Wagg, (void*)&Wq, (void*)&Wk,
        (void*)&Wv, (void*)&bq, (void*)&bk, (void*)&bv, (void*)&Wc,
        (void*)&bc, (void*)&Wg, (void*)&bg,
        (void*)&qallp, (void*)&scp, (void*)&wbar, (void*)&vaggp,
        (void*)&qkvp, (void*)&ub, (void*)&vdp, (void*)&vdiff, (void*)&cbuf
    };
    hipLaunchCooperativeKernel((void*)chain_all, dim3(192), dim3(256),
                               args, 0, stream);
    k9_main<<<B * 32, 256, 0, stream>>>(att, Wg, cbuf, vdiff, rs, out);
}

// Round 11
// 130.129 us; speedup vs baseline: 2.2601x; 2.2601x over previous
//
#include <hip/hip_runtime.h>

#define D 1024
#define B 32
#define NI 1024
#define PP 1000
#define R 3
#define SPLITS 8        // split-K factor for weight GEMMs (K chunk = 128)
#define VS 8            // p-split factor for v_agg (128 padded p each)
#define BK 32
#define KT (D / SPLITS / BK)   // k-tiles per split
#define PAD 34          // row pad (floats): b64 reads land 2-way-conflict only (free)

typedef float f32x4_t __attribute__((ext_vector_type(4)));

__device__ __forceinline__ void nt_store4(float* p, float4 v) {
    f32x4_t x = {v.x, v.y, v.z, v.w};
    __builtin_nontemporal_store(x, (f32x4_t*)p);
}

__device__ __forceinline__ float wred(float x) {
    #pragma unroll
    for (int off = 32; off; off >>= 1) x += __shfl_xor(x, off, 64);
    return x;
}
__device__ __forceinline__ float wmax(float x) {
    #pragma unroll
    for (int off = 32; off; off >>= 1) x = fmaxf(x, __shfl_xor(x, off, 64));
    return x;
}

// ---------------------------------------------------------------------------
// Tiled GEMM core: C[m, b] = sum_k A[m, k] * X[b, k], K-range [kc0, kc0+D/SPLITS)
// ---------------------------------------------------------------------------
template<int NXS>
__device__ __forceinline__ void gemm_core(
        const float* __restrict__ A, int mbase, int Mrows,
        const float* __restrict__ Xb, int xrstride, size_t xss,
        int kc0, float acc[4][4]) {
    __shared__ float Ws[128][PAD];
    __shared__ float Xs[32][PAD];
    const int t = threadIdx.x;
    const int ty = t >> 3, tx = t & 7;
    const int m0 = 4 * ty, b0 = 4 * tx;
    const int lrow = t >> 3, lq = t & 7;

    #pragma unroll
    for (int i = 0; i < 4; ++i)
        #pragma unroll
        for (int j = 0; j < 4; ++j) acc[i][j] = 0.f;

    for (int kt = 0; kt < KT; ++kt) {
        const int kc = kc0 + kt * BK;
        #pragma unroll
        for (int rr = 0; rr < 4; ++rr) {
            const int row = lrow + 32 * rr;
            float4 v = make_float4(0.f, 0.f, 0.f, 0.f);
            if (mbase + row < Mrows)
                v = *(const float4*)(A + (size_t)(mbase + row) * D + kc + 4 * lq);
            *(float2*)&Ws[row][4 * lq]     = make_float2(v.x, v.y);
            *(float2*)&Ws[row][4 * lq + 2] = make_float2(v.z, v.w);
        }
        {
            const float* xp = Xb + (size_t)lrow * xrstride + kc + 4 * lq;
            float4 v = *(const float4*)xp;
            #pragma unroll
            for (int s = 1; s < NXS; ++s) {
                float4 w = *(const float4*)(xp + (size_t)s * xss);
                v.x += w.x; v.y += w.y; v.z += w.z; v.w += w.w;
            }
            *(float2*)&Xs[lrow][4 * lq]     = make_float2(v.x, v.y);
            *(float2*)&Xs[lrow][4 * lq + 2] = make_float2(v.z, v.w);
        }
        __syncthreads();
        #pragma unroll
        for (int kp = 0; kp < 16; ++kp) {
            float2 wv[4], xv[4];
            #pragma unroll
            for (int i = 0; i < 4; ++i) wv[i] = *(const float2*)&Ws[m0 + i][2 * kp];
            #pragma unroll
            for (int j = 0; j < 4; ++j) xv[j] = *(const float2*)&Xs[b0 + j][2 * kp];
            #pragma unroll
            for (int i = 0; i < 4; ++i)
                #pragma unroll
                for (int j = 0; j < 4; ++j) {
                    acc[i][j] += wv[i].x * xv[j].x;
                    acc[i][j] += wv[i].y * xv[j].y;
                }
        }
        __syncthreads();
    }
}

// K1: qall partials. Cp layout: [s][b][3072]
__global__ __launch_bounds__(256) void gemm_k1(const float* __restrict__ Wagg,
        const float* __restrict__ fc, float* __restrict__ Cp) {
    const int mb = blockIdx.x, s = blockIdx.y;
    const int mbase = mb * 128;
    float acc[4][4];
    gemm_core<1>(Wagg, mbase, R * D, fc, D, 0, s * 128, acc);
    const int t = threadIdx.x, ty = t >> 3, tx = t & 7;
    const int m = mbase + 4 * ty;
    #pragma unroll
    for (int j = 0; j < 4; ++j) {
        float* cp = Cp + ((size_t)(s * B) + 4 * tx + j) * (R * D) + m;
        *(float4*)cp = make_float4(acc[0][j], acc[1][j], acc[2][j], acc[3][j]);
    }
}

// K2: score partials. Cp layout: [s][r][b][1024] (only m<1000 valid)
__global__ __launch_bounds__(256) void gemm_k2(const float* __restrict__ pool,
        const float* __restrict__ qallp, float* __restrict__ Cp) {
    const int mb = blockIdx.x, s = blockIdx.y, r = blockIdx.z;
    const int mbase = mb * 128;
    float acc[4][4];
    gemm_core<SPLITS>(pool, mbase, PP, qallp + r * D, R * D, (size_t)B * R * D,
                      s * 128, acc);
    const int t = threadIdx.x, ty = t >> 3, tx = t & 7;
    const int m = mbase + 4 * ty;
    if (m >= PP) return;
    #pragma unroll
    for (int j = 0; j < 4; ++j) {
        float* cp = Cp + ((size_t)((s * R + r) * B) + 4 * tx + j) * D + m;
        *(float4*)cp = make_float4(acc[0][j], acc[1][j], acc[2][j], acc[3][j]);
    }
}

// K5: q/k/v partials. z: 0->(Wq,fc,NXS=1), 1->(Wk,vagg), 2->(Wv,vagg).
// Cp layout: [s][kind][b][1024]
__global__ __launch_bounds__(256) void gemm_k5(const float* __restrict__ Wq,
        const float* __restrict__ Wk, const float* __restrict__ Wv,
        const float* __restrict__ fc, const float* __restrict__ vaggp,
        float* __restrict__ Cp) {
    const int mb = blockIdx.x, s = blockIdx.y, z = blockIdx.z;
    const int mbase = mb * 128;
    float acc[4][4];
    if (z == 0)
        gemm_core<1>(Wq, mbase, D, fc, D, 0, s * 128, acc);
    else
        gemm_core<VS>((z == 1) ? Wk : Wv, mbase, D, vaggp, D, (size_t)B * D,
                      s * 128, acc);
    const int t = threadIdx.x, ty = t >> 3, tx = t & 7;
    const int m = mbase + 4 * ty;
    #pragma unroll
    for (int j = 0; j < 4; ++j) {
        float* cp = Cp + ((size_t)((s * R + z) * B) + 4 * tx + j) * D + m;
        *(float4*)cp = make_float4(acc[0][j], acc[1][j], acc[2][j], acc[3][j]);
    }
}

// K7: v_diff pre-activation partials. Cp layout: [s][b][1024]
__global__ __launch_bounds__(256) void gemm_k7(const float* __restrict__ Wc,
        const float* __restrict__ u, float* __restrict__ Cp) {
    const int mb = blockIdx.x, s = blockIdx.y;
    const int mbase = mb * 128;
    float acc[4][4];
    gemm_core<1>(Wc, mbase, D, u, D, 0, s * 128, acc);
    const int t = threadIdx.x, ty = t >> 3, tx = t & 7;
    const int m = mbase + 4 * ty;
    #pragma unroll
    for (int j = 0; j < 4; ++j) {
        float* cp = Cp + ((size_t)(s * B) + 4 * tx + j) * D + m;
        *(float4*)cp = make_float4(acc[0][j], acc[1][j], acc[2][j], acc[3][j]);
    }
}

// K3w: per b: for r=0..2 softmax over p of summed score partials; accumulate
// wbar[b][p] = (1/3) sum_r softmax_r[p], zero-padded to 1024.
__global__ __launch_bounds__(256) void k3_wbar(const float* __restrict__ scp,
        float* __restrict__ wbar) {
    const int b = blockIdx.x;
    const int t = threadIdx.x, w = t >> 6, lane = t & 63;
    __shared__ float red[8];
    float wb[4] = {0.f, 0.f, 0.f, 0.f};
    for (int r = 0; r < R; ++r) {
        float v[4];
        float mx = -1e30f;
        #pragma unroll
        for (int i = 0; i < 4; ++i) {
            const int p = t + 256 * i;
            float x = -1e30f;
            if (p < PP) {
                x = 0.f;
                #pragma unroll
                for (int s = 0; s < SPLITS; ++s)
                    x += scp[((size_t)((s * R + r) * B) + b) * D + p];
                x *= 0.03125f;
            }
            v[i] = x;
            mx = fmaxf(mx, x);
        }
        mx = wmax(mx);
        if (lane == 0) red[w] = mx;
        __syncthreads();
        mx = fmaxf(fmaxf(red[0], red[1]), fmaxf(red[2], red[3]));
        float e[4], sum = 0.f;
        #pragma unroll
        for (int i = 0; i < 4; ++i) {
            const int p = t + 256 * i;
            e[i] = (p < PP) ? __expf(v[i] - mx) : 0.f;
            sum += e[i];
        }
        sum = wred(sum);
        if (lane == 0) red[4 + w] = sum;
        __syncthreads();
        const float inv = 1.f / (red[4] + red[5] + red[6] + red[7]);
        #pragma unroll
        for (int i = 0; i < 4; ++i) wb[i] += e[i] * inv;
        __syncthreads();
    }
    #pragma unroll
    for (int i = 0; i < 4; ++i) {
        const int p = t + 256 * i;
        wbar[(size_t)b * 1024 + p] = wb[i] * (1.f / 3.f);
    }
}

// K4: v_agg partials as micro-tiled GEMM over p.
__global__ __launch_bounds__(256) void k4_vagg(const float* __restrict__ wbar,
        const float* __restrict__ pool, float* __restrict__ vaggp) {
    const int db = blockIdx.x, ps = blockIdx.y;
    __shared__ float Ps[32][132];
    __shared__ float Wbt[32][36];
    const int t = threadIdx.x;
    const int ty = t >> 3, tx = t & 7;
    float acc[4][4];
    #pragma unroll
    for (int i = 0; i < 4; ++i)
        #pragma unroll
        for (int j = 0; j < 4; ++j) acc[i][j] = 0.f;

    for (int pt = 0; pt < 4; ++pt) {
        const int p0 = ps * 128 + pt * 32;
        {
            const int prow = t >> 5, qc = t & 31;
            #pragma unroll
            for (int rr = 0; rr < 4; ++rr) {
                const int pr = prow + 8 * rr;
                float4 v = make_float4(0.f, 0.f, 0.f, 0.f);
                if (p0 + pr < PP)
                    v = *(const float4*)(pool + (size_t)(p0 + pr) * D + db * 128 + 4 * qc);
                *(float4*)&Ps[pr][4 * qc] = v;
            }
        }
        {
            const int bb = t >> 3, q = t & 7;
            float4 v = *(const float4*)(wbar + (size_t)bb * 1024 + p0 + 4 * q);
            Wbt[4 * q + 0][bb] = v.x; Wbt[4 * q + 1][bb] = v.y;
            Wbt[4 * q + 2][bb] = v.z; Wbt[4 * q + 3][bb] = v.w;
        }
        __syncthreads();
        #pragma unroll
        for (int pg = 0; pg < 8; ++pg) {
            #pragma unroll
            for (int pp = 0; pp < 4; ++pp) {
                const int p = 4 * pg + pp;
                float4 xv = *(const float4*)&Ps[p][4 * ty];
                float4 wv = *(const float4*)&Wbt[p][4 * tx];
                const float xs[4] = {xv.x, xv.y, xv.z, xv.w};
                const float wsv[4] = {wv.x, wv.y, wv.z, wv.w};
                #pragma unroll
                for (int i = 0; i < 4; ++i)
                    #pragma unroll
                    for (int j = 0; j < 4; ++j)
                        acc[i][j] += xs[i] * wsv[j];
            }
        }
        __syncthreads();
    }
    const int dbase = db * 128 + 4 * ty;
    #pragma unroll
    for (int j = 0; j < 4; ++j) {
        float* op = vaggp + ((size_t)ps * B + 4 * tx + j) * D + dbase;
        *(float4*)op = make_float4(acc[0][j], acc[1][j], acc[2][j], acc[3][j]);
    }
}

// K6: sum qkv partials (+bias), sim = scale*dot(q,k), u = vhat - sigmoid(sim)*v
__global__ __launch_bounds__(256) void k6_u(const float* __restrict__ qkvp,
        const float* __restrict__ bq, const float* __restrict__ bk,
        const float* __restrict__ bv, const float* __restrict__ vhat,
        float* __restrict__ u) {
    const int b = blockIdx.x;
    const int t = threadIdx.x, w = t >> 6, lane = t & 63;
    const int d = 4 * t;
    float4 qv = *(const float4*)(bq + d);
    float4 kv = *(const float4*)(bk + d);
    #pragma unroll
    for (int s = 0; s < SPLITS; ++s) {
        float4 a = *(const float4*)(qkvp + ((size_t)((s * R + 0) * B) + b) * D + d);
        float4 c = *(const float4*)(qkvp + ((size_t)((s * R + 1) * B) + b) * D + d);
        qv.x += a.x; qv.y += a.y; qv.z += a.z; qv.w += a.w;
        kv.x += c.x; kv.y += c.y; kv.z += c.z; kv.w += c.w;
    }
    float local = qv.x * kv.x + qv.y * kv.y + qv.z * kv.z + qv.w * kv.w;
    local = wred(local);
    __shared__ float red[4];
    if (lane == 0) red[w] = local;
    __syncthreads();
    const float sim = (red[0] + red[1] + red[2] + red[3]) * 0.03125f;
    const float sig = 1.f / (1.f + __expf(-sim));
    float4 vv = *(const float4*)(bv + d);
    #pragma unroll
    for (int s = 0; s < SPLITS; ++s) {
        float4 c = *(const float4*)(qkvp + ((size_t)((s * R + 2) * B) + b) * D + d);
        vv.x += c.x; vv.y += c.y; vv.z += c.z; vv.w += c.w;
    }
    const float4 vh = *(const float4*)(vhat + (size_t)b * D + d);
    float4 o;
    o.x = vh.x - sig * vv.x; o.y = vh.y - sig * vv.y;
    o.z = vh.z - sig * vv.z; o.w = vh.w - sig * vv.w;
    *(float4*)(u + (size_t)b * D + d) = o;
}

// K8: vdiff[b,d] = relu(sum_s vdp + bc); cb[b] = dot(vdiff[b], Wg2) + bg
__global__ __launch_bounds__(256) void k8_cb(const float* __restrict__ vdp,
        const float* __restrict__ bc, const float* __restrict__ Wg,
        const float* __restrict__ bg, float* __restrict__ vdiff,
        float* __restrict__ cb) {
    const int b = blockIdx.x;
    const int t = threadIdx.x, w = t >> 6, lane = t & 63;
    const int d = 4 * t;
    float4 a = *(const float4*)(bc + d);
    #pragma unroll
    for (int s = 0; s < SPLITS; ++s) {
        float4 c = *(const float4*)(vdp + ((size_t)(s * B) + b) * D + d);
        a.x += c.x; a.y += c.y; a.z += c.z; a.w += c.w;
    }
    a.x = fmaxf(a.x, 0.f); a.y = fmaxf(a.y, 0.f);
    a.z = fmaxf(a.z, 0.f); a.w = fmaxf(a.w, 0.f);
    *(float4*)(vdiff + (size_t)b * D + d) = a;
    const float4 g2 = *(const float4*)(Wg + D + d);
    float local = a.x * g2.x + a.y * g2.y + a.z * g2.z + a.w * g2.w;
    local = wred(local);
    __shared__ float red[4];
    if (lane == 0) red[w] = local;
    __syncthreads();
    if (t == 0) cb[b] = red[0] + red[1] + red[2] + red[3] + bg[0];
}

// K9: out[b,n,d] = att + rs * sigmoid(att[b,n,:].Wg1 + cb[b]) * vdiff[b,d]
// Persistent pipelined; asm "memory" fence after the nxt-load issue FORCES
// the loads to issue before the dot/reduce/store phase (the allocator was
// sinking them in rounds 6/9 — VGPR stayed 64). Register-only compute still
// schedules after the fence; stores can't move above it (they're below anyway).
__global__ __launch_bounds__(256, 2) void k9_main(const float* __restrict__ att,
        const float* __restrict__ Wg, const float* __restrict__ cb,
        const float* __restrict__ vdiff, const float* __restrict__ rs_p,
        float* __restrict__ out) {
    __shared__ float vds[1024];
    const int t = threadIdx.x;
    const int b = blockIdx.x >> 5;          // 32 blocks per batch
    *(float4*)&vds[4 * t] = *(const float4*)(vdiff + (size_t)b * D + 4 * t);
    __syncthreads();
    const int w = t >> 6, lane = t & 63;
    float4 g[4];
    #pragma unroll
    for (int kk = 0; kk < 4; ++kk)
        g[kk] = *(const float4*)(Wg + 4 * lane + 256 * kk);
    const float rsv = rs_p[0];
    const float cbb = cb[b];
    const size_t row0 = (size_t)b * NI + (size_t)(blockIdx.x & 31) * 32 + w * 8;
    const float* ap = att + row0 * D;
    float* op = out + row0 * D;

    float4 cur[8], nxt[8];
    #pragma unroll
    for (int q = 0; q < 8; ++q)
        cur[q] = *(const float4*)(ap + (size_t)(q >> 2) * D + 4 * lane + 256 * (q & 3));
    asm volatile("" ::: "memory");   // pin cur loads' issue point

    #pragma unroll
    for (int it = 0; it < 4; ++it) {
        if (it < 3) {
            const float* apn = ap + (size_t)(2 * it + 2) * D;
            #pragma unroll
            for (int q = 0; q < 8; ++q)
                nxt[q] = *(const float4*)(apn + (size_t)(q >> 2) * D + 4 * lane + 256 * (q & 3));
            asm volatile("" ::: "memory");   // force nxt loads to ISSUE here
        }
        float acc0 = 0.f, acc1 = 0.f;
        #pragma unroll
        for (int kk = 0; kk < 4; ++kk) {
            acc0 += cur[kk].x * g[kk].x + cur[kk].y * g[kk].y +
                    cur[kk].z * g[kk].z + cur[kk].w * g[kk].w;
            acc1 += cur[4 + kk].x * g[kk].x + cur[4 + kk].y * g[kk].y +
                    cur[4 + kk].z * g[kk].z + cur[4 + kk].w * g[kk].w;
        }
        #pragma unroll
        for (int off = 32; off; off >>= 1) {
            acc0 += __shfl_xor(acc0, off, 64);
            acc1 += __shfl_xor(acc1, off, 64);
        }
        const float grs0 = rsv / (1.f + __expf(-(acc0 + cbb)));
        const float grs1 = rsv / (1.f + __expf(-(acc1 + cbb)));
        float* op0 = op + (size_t)(2 * it) * D;
        #pragma unroll
        for (int kk = 0; kk < 4; ++kk) {
            const int col = 4 * lane + 256 * kk;
            const float4 vd = *(const float4*)&vds[col];
            float4 o0, o1;
            o0.x = cur[kk].x + grs0 * vd.x; o0.y = cur[kk].y + grs0 * vd.y;
            o0.z = cur[kk].z + grs0 * vd.z; o0.w = cur[kk].w + grs0 * vd.w;
            o1.x = cur[4 + kk].x + grs1 * vd.x; o1.y = cur[4 + kk].y + grs1 * vd.y;
            o1.z = cur[4 + kk].z + grs1 * vd.z; o1.w = cur[4 + kk].w + grs1 * vd.w;
            nt_store4(op0 + col, o0);
            nt_store4(op0 + D + col, o1);
        }
        if (it < 3) {
            #pragma unroll
            for (int q = 0; q < 8; ++q) cur[q] = nxt[q];
        }
    }
}

extern "C" void kernel_launch(void* const* d_in, const int* in_sizes, int n_in,
                              void* d_out, int out_size, void* d_ws, size_t ws_size,
                              hipStream_t stream) {
    const float* att  = (const float*)d_in[0];
    const float* fc   = (const float*)d_in[1];
    const float* pool = (const float*)d_in[2];
    const float* Wagg = (const float*)d_in[3];
    const float* Wq   = (const float*)d_in[4];
    const float* bq   = (const float*)d_in[5];
    const float* Wk   = (const float*)d_in[6];
    const float* bk   = (const float*)d_in[7];
    const float* Wv   = (const float*)d_in[8];
    const float* bv   = (const float*)d_in[9];
    const float* Wc   = (const float*)d_in[10];
    const float* bc   = (const float*)d_in[11];
    const float* Wg   = (const float*)d_in[12];
    const float* bg   = (const float*)d_in[13];
    const float* rs   = (const float*)d_in[14];
    float* out = (float*)d_out;

    float* ws = (float*)d_ws;
    float* qallp = ws;                                  // SPLITS*B*R*D
    float* scp   = qallp + (size_t)SPLITS * B * R * D;  // SPLITS*R*B*D
    float* wbar  = scp + (size_t)SPLITS * R * B * D;    // B*1024
    float* vaggp = wbar + (size_t)B * 1024;             // VS*B*D
    float* qkvp  = vaggp + (size_t)VS * B * D;          // SPLITS*R*B*D
    float* ub    = qkvp + (size_t)SPLITS * R * B * D;   // B*D
    float* vdp   = ub + (size_t)B * D;                  // SPLITS*B*D
    float* vdiff = vdp + (size_t)SPLITS * B * D;        // B*D
    float* cbuf  = vdiff + (size_t)B * D;               // B

    gemm_k1<<<dim3(24, SPLITS), 256, 0, stream>>>(Wagg, fc, qallp);
    gemm_k2<<<dim3(8, SPLITS, R), 256, 0, stream>>>(pool, qallp, scp);
    k3_wbar<<<B, 256, 0, stream>>>(scp, wbar);
    k4_vagg<<<dim3(8, VS), 256, 0, stream>>>(wbar, pool, vaggp);
    gemm_k5<<<dim3(8, SPLITS, R), 256, 0, stream>>>(Wq, Wk, Wv, fc, vaggp, qkvp);
    k6_u<<<B, 256, 0, stream>>>(qkvp, bq, bk, bv, fc, ub);
    gemm_k7<<<dim3(8, SPLITS), 256, 0, stream>>>(Wc, ub, vdp);
    k8_cb<<<B, 256, 0, stream>>>(vdp, bc, Wg, bg, vdiff, cbuf);
    k9_main<<<B * 32, 256, 0, stream>>>(att, Wg, cbuf, vdiff, rs, out);
}

// Round 12
// 129.794 us; speedup vs baseline: 2.2659x; 1.0026x over previous
//
#include <hip/hip_runtime.h>

#define D 1024
#define B 32
#define NI 1024
#define PP 1000
#define R 3
#define SPLITS 8        // split-K factor for weight GEMMs (K chunk = 128)
#define VS 8            // p-split factor for v_agg (128 padded p each)
#define BK 32
#define KT (D / SPLITS / BK)   // k-tiles per split
#define PAD 34          // row pad (floats): b64 reads land 2-way-conflict only (free)

typedef float f32x4_t __attribute__((ext_vector_type(4)));

__device__ __forceinline__ void nt_store4v(float* p, f32x4_t x) {
    __builtin_nontemporal_store(x, (f32x4_t*)p);
}

__device__ __forceinline__ float wred(float x) {
    #pragma unroll
    for (int off = 32; off; off >>= 1) x += __shfl_xor(x, off, 64);
    return x;
}
__device__ __forceinline__ float wmax(float x) {
    #pragma unroll
    for (int off = 32; off; off >>= 1) x = fmaxf(x, __shfl_xor(x, off, 64));
    return x;
}

// ---------------------------------------------------------------------------
// Tiled GEMM core: C[m, b] = sum_k A[m, k] * X[b, k], K-range [kc0, kc0+D/SPLITS)
// ---------------------------------------------------------------------------
template<int NXS>
__device__ __forceinline__ void gemm_core(
        const float* __restrict__ A, int mbase, int Mrows,
        const float* __restrict__ Xb, int xrstride, size_t xss,
        int kc0, float acc[4][4]) {
    __shared__ float Ws[128][PAD];
    __shared__ float Xs[32][PAD];
    const int t = threadIdx.x;
    const int ty = t >> 3, tx = t & 7;
    const int m0 = 4 * ty, b0 = 4 * tx;
    const int lrow = t >> 3, lq = t & 7;

    #pragma unroll
    for (int i = 0; i < 4; ++i)
        #pragma unroll
        for (int j = 0; j < 4; ++j) acc[i][j] = 0.f;

    for (int kt = 0; kt < KT; ++kt) {
        const int kc = kc0 + kt * BK;
        #pragma unroll
        for (int rr = 0; rr < 4; ++rr) {
            const int row = lrow + 32 * rr;
            float4 v = make_float4(0.f, 0.f, 0.f, 0.f);
            if (mbase + row < Mrows)
                v = *(const float4*)(A + (size_t)(mbase + row) * D + kc + 4 * lq);
            *(float2*)&Ws[row][4 * lq]     = make_float2(v.x, v.y);
            *(float2*)&Ws[row][4 * lq + 2] = make_float2(v.z, v.w);
        }
        {
            const float* xp = Xb + (size_t)lrow * xrstride + kc + 4 * lq;
            float4 v = *(const float4*)xp;
            #pragma unroll
            for (int s = 1; s < NXS; ++s) {
                float4 w = *(const float4*)(xp + (size_t)s * xss);
                v.x += w.x; v.y += w.y; v.z += w.z; v.w += w.w;
            }
            *(float2*)&Xs[lrow][4 * lq]     = make_float2(v.x, v.y);
            *(float2*)&Xs[lrow][4 * lq + 2] = make_float2(v.z, v.w);
        }
        __syncthreads();
        #pragma unroll
        for (int kp = 0; kp < 16; ++kp) {
            float2 wv[4], xv[4];
            #pragma unroll
            for (int i = 0; i < 4; ++i) wv[i] = *(const float2*)&Ws[m0 + i][2 * kp];
            #pragma unroll
            for (int j = 0; j < 4; ++j) xv[j] = *(const float2*)&Xs[b0 + j][2 * kp];
            #pragma unroll
            for (int i = 0; i < 4; ++i)
                #pragma unroll
                for (int j = 0; j < 4; ++j) {
                    acc[i][j] += wv[i].x * xv[j].x;
                    acc[i][j] += wv[i].y * xv[j].y;
                }
        }
        __syncthreads();
    }
}

// K1q: qall partials (mb<24) and q partials (mb>=24). Both X=fc, NXS=1.
__global__ __launch_bounds__(256) void gemm_k1q(const float* __restrict__ Wagg,
        const float* __restrict__ Wq, const float* __restrict__ fc,
        float* __restrict__ qallp, float* __restrict__ qkvp) {
    const int mb = blockIdx.x, s = blockIdx.y;
    const int t = threadIdx.x, ty = t >> 3, tx = t & 7;
    float acc[4][4];
    if (mb < 24) {
        const int mbase = mb * 128;
        gemm_core<1>(Wagg, mbase, R * D, fc, D, 0, s * 128, acc);
        const int m = mbase + 4 * ty;
        #pragma unroll
        for (int j = 0; j < 4; ++j) {
            float* cp = qallp + ((size_t)(s * B) + 4 * tx + j) * (R * D) + m;
            *(float4*)cp = make_float4(acc[0][j], acc[1][j], acc[2][j], acc[3][j]);
        }
    } else {
        const int mbase = (mb - 24) * 128;
        gemm_core<1>(Wq, mbase, D, fc, D, 0, s * 128, acc);
        const int m = mbase + 4 * ty;
        #pragma unroll
        for (int j = 0; j < 4; ++j) {
            float* cp = qkvp + ((size_t)((s * R + 0) * B) + 4 * tx + j) * D + m;
            *(float4*)cp = make_float4(acc[0][j], acc[1][j], acc[2][j], acc[3][j]);
        }
    }
}

// K2: score partials. Cp layout: [s][r][b][1024] (only m<1000 valid)
__global__ __launch_bounds__(256) void gemm_k2(const float* __restrict__ pool,
        const float* __restrict__ qallp, float* __restrict__ Cp) {
    const int mb = blockIdx.x, s = blockIdx.y, r = blockIdx.z;
    const int mbase = mb * 128;
    float acc[4][4];
    gemm_core<SPLITS>(pool, mbase, PP, qallp + r * D, R * D, (size_t)B * R * D,
                      s * 128, acc);
    const int t = threadIdx.x, ty = t >> 3, tx = t & 7;
    const int m = mbase + 4 * ty;
    if (m >= PP) return;
    #pragma unroll
    for (int j = 0; j < 4; ++j) {
        float* cp = Cp + ((size_t)((s * R + r) * B) + 4 * tx + j) * D + m;
        *(float4*)cp = make_float4(acc[0][j], acc[1][j], acc[2][j], acc[3][j]);
    }
}

// K5kv: k/v partials. z: 0->Wk (kind 1), 1->Wv (kind 2). X = sum of VS vagg partials.
__global__ __launch_bounds__(256) void gemm_k5kv(const float* __restrict__ Wk,
        const float* __restrict__ Wv, const float* __restrict__ vaggp,
        float* __restrict__ Cp) {
    const int mb = blockIdx.x, s = blockIdx.y, z = blockIdx.z;
    const int mbase = mb * 128;
    float acc[4][4];
    gemm_core<VS>((z == 0) ? Wk : Wv, mbase, D, vaggp, D, (size_t)B * D,
                  s * 128, acc);
    const int t = threadIdx.x, ty = t >> 3, tx = t & 7;
    const int m = mbase + 4 * ty;
    #pragma unroll
    for (int j = 0; j < 4; ++j) {
        float* cp = Cp + ((size_t)((s * R + z + 1) * B) + 4 * tx + j) * D + m;
        *(float4*)cp = make_float4(acc[0][j], acc[1][j], acc[2][j], acc[3][j]);
    }
}

// K7: v_diff pre-activation partials. Cp layout: [s][b][1024]
__global__ __launch_bounds__(256) void gemm_k7(const float* __restrict__ Wc,
        const float* __restrict__ u, float* __restrict__ Cp) {
    const int mb = blockIdx.x, s = blockIdx.y;
    const int mbase = mb * 128;
    float acc[4][4];
    gemm_core<1>(Wc, mbase, D, u, D, 0, s * 128, acc);
    const int t = threadIdx.x, ty = t >> 3, tx = t & 7;
    const int m = mbase + 4 * ty;
    #pragma unroll
    for (int j = 0; j < 4; ++j) {
        float* cp = Cp + ((size_t)(s * B) + 4 * tx + j) * D + m;
        *(float4*)cp = make_float4(acc[0][j], acc[1][j], acc[2][j], acc[3][j]);
    }
}

// K3w: per b: for r=0..2 softmax over p of summed score partials; accumulate
// wbar[b][p] = (1/3) sum_r softmax_r[p], zero-padded to 1024.
__global__ __launch_bounds__(256) void k3_wbar(const float* __restrict__ scp,
        float* __restrict__ wbar) {
    const int b = blockIdx.x;
    const int t = threadIdx.x, w = t >> 6, lane = t & 63;
    __shared__ float red[8];
    float wb[4] = {0.f, 0.f, 0.f, 0.f};
    for (int r = 0; r < R; ++r) {
        float v[4];
        float mx = -1e30f;
        #pragma unroll
        for (int i = 0; i < 4; ++i) {
            const int p = t + 256 * i;
            float x = -1e30f;
            if (p < PP) {
                x = 0.f;
                #pragma unroll
                for (int s = 0; s < SPLITS; ++s)
                    x += scp[((size_t)((s * R + r) * B) + b) * D + p];
                x *= 0.03125f;
            }
            v[i] = x;
            mx = fmaxf(mx, x);
        }
        mx = wmax(mx);
        if (lane == 0) red[w] = mx;
        __syncthreads();
        mx = fmaxf(fmaxf(red[0], red[1]), fmaxf(red[2], red[3]));
        float e[4], sum = 0.f;
        #pragma unroll
        for (int i = 0; i < 4; ++i) {
            const int p = t + 256 * i;
            e[i] = (p < PP) ? __expf(v[i] - mx) : 0.f;
            sum += e[i];
        }
        sum = wred(sum);
        if (lane == 0) red[4 + w] = sum;
        __syncthreads();
        const float inv = 1.f / (red[4] + red[5] + red[6] + red[7]);
        #pragma unroll
        for (int i = 0; i < 4; ++i) wb[i] += e[i] * inv;
        __syncthreads();
    }
    #pragma unroll
    for (int i = 0; i < 4; ++i) {
        const int p = t + 256 * i;
        wbar[(size_t)b * 1024 + p] = wb[i] * (1.f / 3.f);
    }
}

// K4: v_agg partials as micro-tiled GEMM over p.
__global__ __launch_bounds__(256) void k4_vagg(const float* __restrict__ wbar,
        const float* __restrict__ pool, float* __restrict__ vaggp) {
    const int db = blockIdx.x, ps = blockIdx.y;
    __shared__ float Ps[32][132];
    __shared__ float Wbt[32][36];
    const int t = threadIdx.x;
    const int ty = t >> 3, tx = t & 7;
    float acc[4][4];
    #pragma unroll
    for (int i = 0; i < 4; ++i)
        #pragma unroll
        for (int j = 0; j < 4; ++j) acc[i][j] = 0.f;

    for (int pt = 0; pt < 4; ++pt) {
        const int p0 = ps * 128 + pt * 32;
        {
            const int prow = t >> 5, qc = t & 31;
            #pragma unroll
            for (int rr = 0; rr < 4; ++rr) {
                const int pr = prow + 8 * rr;
                float4 v = make_float4(0.f, 0.f, 0.f, 0.f);
                if (p0 + pr < PP)
                    v = *(const float4*)(pool + (size_t)(p0 + pr) * D + db * 128 + 4 * qc);
                *(float4*)&Ps[pr][4 * qc] = v;
            }
        }
        {
            const int bb = t >> 3, q = t & 7;
            float4 v = *(const float4*)(wbar + (size_t)bb * 1024 + p0 + 4 * q);
            Wbt[4 * q + 0][bb] = v.x; Wbt[4 * q + 1][bb] = v.y;
            Wbt[4 * q + 2][bb] = v.z; Wbt[4 * q + 3][bb] = v.w;
        }
        __syncthreads();
        #pragma unroll
        for (int pg = 0; pg < 8; ++pg) {
            #pragma unroll
            for (int pp = 0; pp < 4; ++pp) {
                const int p = 4 * pg + pp;
                float4 xv = *(const float4*)&Ps[p][4 * ty];
                float4 wv = *(const float4*)&Wbt[p][4 * tx];
                const float xs[4] = {xv.x, xv.y, xv.z, xv.w};
                const float wsv[4] = {wv.x, wv.y, wv.z, wv.w};
                #pragma unroll
                for (int i = 0; i < 4; ++i)
                    #pragma unroll
                    for (int j = 0; j < 4; ++j)
                        acc[i][j] += xs[i] * wsv[j];
            }
        }
        __syncthreads();
    }
    const int dbase = db * 128 + 4 * ty;
    #pragma unroll
    for (int j = 0; j < 4; ++j) {
        float* op = vaggp + ((size_t)ps * B + 4 * tx + j) * D + dbase;
        *(float4*)op = make_float4(acc[0][j], acc[1][j], acc[2][j], acc[3][j]);
    }
}

// K6: sum qkv partials (+bias), sim = scale*dot(q,k), u = vhat - sigmoid(sim)*v
__global__ __launch_bounds__(256) void k6_u(const float* __restrict__ qkvp,
        const float* __restrict__ bq, const float* __restrict__ bk,
        const float* __restrict__ bv, const float* __restrict__ vhat,
        float* __restrict__ u) {
    const int b = blockIdx.x;
    const int t = threadIdx.x, w = t >> 6, lane = t & 63;
    const int d = 4 * t;
    float4 qv = *(const float4*)(bq + d);
    float4 kv = *(const float4*)(bk + d);
    #pragma unroll
    for (int s = 0; s < SPLITS; ++s) {
        float4 a = *(const float4*)(qkvp + ((size_t)((s * R + 0) * B) + b) * D + d);
        float4 c = *(const float4*)(qkvp + ((size_t)((s * R + 1) * B) + b) * D + d);
        qv.x += a.x; qv.y += a.y; qv.z += a.z; qv.w += a.w;
        kv.x += c.x; kv.y += c.y; kv.z += c.z; kv.w += c.w;
    }
    float local = qv.x * kv.x + qv.y * kv.y + qv.z * kv.z + qv.w * kv.w;
    local = wred(local);
    __shared__ float red[4];
    if (lane == 0) red[w] = local;
    __syncthreads();
    const float sim = (red[0] + red[1] + red[2] + red[3]) * 0.03125f;
    const float sig = 1.f / (1.f + __expf(-sim));
    float4 vv = *(const float4*)(bv + d);
    #pragma unroll
    for (int s = 0; s < SPLITS; ++s) {
        float4 c = *(const float4*)(qkvp + ((size_t)((s * R + 2) * B) + b) * D + d);
        vv.x += c.x; vv.y += c.y; vv.z += c.z; vv.w += c.w;
    }
    const float4 vh = *(const float4*)(vhat + (size_t)b * D + d);
    float4 o;
    o.x = vh.x - sig * vv.x; o.y = vh.y - sig * vv.y;
    o.z = vh.z - sig * vv.z; o.w = vh.w - sig * vv.w;
    *(float4*)(u + (size_t)b * D + d) = o;
}

// K8: vdiff[b,d] = relu(sum_s vdp + bc); cb[b] = dot(vdiff[b], Wg2) + bg
__global__ __launch_bounds__(256) void k8_cb(const float* __restrict__ vdp,
        const float* __restrict__ bc, const float* __restrict__ Wg,
        const float* __restrict__ bg, float* __restrict__ vdiff,
        float* __restrict__ cb) {
    const int b = blockIdx.x;
    const int t = threadIdx.x, w = t >> 6, lane = t & 63;
    const int d = 4 * t;
    float4 a = *(const float4*)(bc + d);
    #pragma unroll
    for (int s = 0; s < SPLITS; ++s) {
        float4 c = *(const float4*)(vdp + ((size_t)(s * B) + b) * D + d);
        a.x += c.x; a.y += c.y; a.z += c.z; a.w += c.w;
    }
    a.x = fmaxf(a.x, 0.f); a.y = fmaxf(a.y, 0.f);
    a.z = fmaxf(a.z, 0.f); a.w = fmaxf(a.w, 0.f);
    *(float4*)(vdiff + (size_t)b * D + d) = a;
    const float4 g2 = *(const float4*)(Wg + D + d);
    float local = a.x * g2.x + a.y * g2.y + a.z * g2.z + a.w * g2.w;
    local = wred(local);
    __shared__ float red[4];
    if (lane == 0) red[w] = local;
    __syncthreads();
    if (t == 0) cb[b] = red[0] + red[1] + red[2] + red[3] + bg[0];
}

// K9: out[b,n,d] = att + rs * sigmoid(att[b,n,:].Wg1 + cb[b]) * vdiff[b,d]
// asm-volatile pipelined: loads are inline-asm global_load_dwordx4 (compiler
// CANNOT sink/merge them) with hand-counted s_waitcnt vmcnt(N) — wait only
// for the previous pair's 8 loads while the next pair's loads + this pair's
// stores stay in flight (AITER T4 pattern). sched_barrier(0) after each
// waitcnt per guide rule #18.
#define LD16(dst, srcp) \
    asm volatile("global_load_dwordx4 %0, %1, off" : "=v"(dst) : "v"(srcp) : "memory")

__global__ __launch_bounds__(256) void k9_main(const float* __restrict__ att,
        const float* __restrict__ Wg, const float* __restrict__ cb,
        const float* __restrict__ vdiff, const float* __restrict__ rs_p,
        float* __restrict__ out) {
    __shared__ float vds[1024];
    const int t = threadIdx.x;
    const int b = blockIdx.x >> 5;          // 32 blocks per batch, 32 rows/block
    *(float4*)&vds[4 * t] = *(const float4*)(vdiff + (size_t)b * D + 4 * t);
    __syncthreads();
    const int w = t >> 6, lane = t & 63;
    float4 g[4];
    #pragma unroll
    for (int kk = 0; kk < 4; ++kk)
        g[kk] = *(const float4*)(Wg + 4 * lane + 256 * kk);
    const float rsv = rs_p[0];
    const float cbb = cb[b];
    const size_t row0 = (size_t)blockIdx.x * 32 + w * 8;   // 8 rows per wave
    const float* ap = att + row0 * D;
    float* op = out + row0 * D;
    const int co = 4 * lane;

    f32x4_t bufA[8], bufB[8];

    // compute+store for one row pair held in BUF, rows (base, base+1)
#define PAIR_COMPUTE_STORE(BUF, OPB)                                          \
    {                                                                         \
        float acc0 = 0.f, acc1 = 0.f;                                         \
        _Pragma("unroll")                                                     \
        for (int kk = 0; kk < 4; ++kk) {                                      \
            acc0 += BUF[kk][0] * g[kk].x + BUF[kk][1] * g[kk].y +             \
                    BUF[kk][2] * g[kk].z + BUF[kk][3] * g[kk].w;              \
            acc1 += BUF[4 + kk][0] * g[kk].x + BUF[4 + kk][1] * g[kk].y +     \
                    BUF[4 + kk][2] * g[kk].z + BUF[4 + kk][3] * g[kk].w;      \
        }                                                                     \
        _Pragma("unroll")                                                     \
        for (int off = 32; off; off >>= 1) {                                  \
            acc0 += __shfl_xor(acc0, off, 64);                                \
            acc1 += __shfl_xor(acc1, off, 64);                                \
        }                                                                     \
        const float grs0 = rsv / (1.f + __expf(-(acc0 + cbb)));               \
        const float grs1 = rsv / (1.f + __expf(-(acc1 + cbb)));               \
        _Pragma("unroll")                                                     \
        for (int kk = 0; kk < 4; ++kk) {                                      \
            const int col = co + 256 * kk;                                    \
            const float4 vd = *(const float4*)&vds[col];                      \
            f32x4_t o0, o1;                                                   \
            o0[0] = BUF[kk][0] + grs0 * vd.x; o0[1] = BUF[kk][1] + grs0 * vd.y; \
            o0[2] = BUF[kk][2] + grs0 * vd.z; o0[3] = BUF[kk][3] + grs0 * vd.w; \
            o1[0] = BUF[4 + kk][0] + grs1 * vd.x; o1[1] = BUF[4 + kk][1] + grs1 * vd.y; \
            o1[2] = BUF[4 + kk][2] + grs1 * vd.z; o1[3] = BUF[4 + kk][3] + grs1 * vd.w; \
            nt_store4v((OPB) + col, o0);                                      \
            nt_store4v((OPB) + D + col, o1);                                  \
        }                                                                     \
    }

#define ISSUE_PAIR(BUF, ROWOFF)                                               \
    _Pragma("unroll")                                                         \
    for (int q = 0; q < 8; ++q) {                                             \
        const float* _src = ap + (size_t)((ROWOFF) + (q >> 2)) * D + co + 256 * (q & 3); \
        LD16(BUF[q], _src);                                                   \
    }

    // prologue: pair0 -> bufA, drain
    ISSUE_PAIR(bufA, 0);
    asm volatile("s_waitcnt vmcnt(0)");
    __builtin_amdgcn_sched_barrier(0);

    // it0: issue pair1 -> bufB; compute pair0; store (8)
    ISSUE_PAIR(bufB, 2);
    PAIR_COMPUTE_STORE(bufA, op);

    // it1: issue pair2 -> bufA; wait pair1 (Q: [p1(8), st0(8), p2(8)] -> 16)
    ISSUE_PAIR(bufA, 4);
    asm volatile("s_waitcnt vmcnt(16)");
    __builtin_amdgcn_sched_barrier(0);
    PAIR_COMPUTE_STORE(bufB, op + 2 * D);

    // it2: issue pair3 -> bufB; wait pair2 (Q: [st0?, p2, st1, p3] -> 16)
    ISSUE_PAIR(bufB, 6);
    asm volatile("s_waitcnt vmcnt(16)");
    __builtin_amdgcn_sched_barrier(0);
    PAIR_COMPUTE_STORE(bufA, op + 4 * D);

    // it3: wait pair3 (Q: [st1?, p3, st2] -> 8)
    asm volatile("s_waitcnt vmcnt(8)");
    __builtin_amdgcn_sched_barrier(0);
    PAIR_COMPUTE_STORE(bufB, op + 6 * D);
}

extern "C" void kernel_launch(void* const* d_in, const int* in_sizes, int n_in,
                              void* d_out, int out_size, void* d_ws, size_t ws_size,
                              hipStream_t stream) {
    const float* att  = (const float*)d_in[0];
    const float* fc   = (const float*)d_in[1];
    const float* pool = (const float*)d_in[2];
    const float* Wagg = (const float*)d_in[3];
    const float* Wq   = (const float*)d_in[4];
    const float* bq   = (const float*)d_in[5];
    const float* Wk   = (const float*)d_in[6];
    const float* bk   = (const float*)d_in[7];
    const float* Wv   = (const float*)d_in[8];
    const float* bv   = (const float*)d_in[9];
    const float* Wc   = (const float*)d_in[10];
    const float* bc   = (const float*)d_in[11];
    const float* Wg   = (const float*)d_in[12];
    const float* bg   = (const float*)d_in[13];
    const float* rs   = (const float*)d_in[14];
    float* out = (float*)d_out;

    float* ws = (float*)d_ws;
    float* qallp = ws;                                  // SPLITS*B*R*D
    float* scp   = qallp + (size_t)SPLITS * B * R * D;  // SPLITS*R*B*D
    float* wbar  = scp + (size_t)SPLITS * R * B * D;    // B*1024
    float* vaggp = wbar + (size_t)B * 1024;             // VS*B*D
    float* qkvp  = vaggp + (size_t)VS * B * D;          // SPLITS*R*B*D
    float* ub    = qkvp + (size_t)SPLITS * R * B * D;   // B*D
    float* vdp   = ub + (size_t)B * D;                  // SPLITS*B*D
    float* vdiff = vdp + (size_t)SPLITS * B * D;        // B*D
    float* cbuf  = vdiff + (size_t)B * D;               // B

    gemm_k1q<<<dim3(32, SPLITS), 256, 0, stream>>>(Wagg, Wq, fc, qallp, qkvp);
    gemm_k2<<<dim3(8, SPLITS, R), 256, 0, stream>>>(pool, qallp, scp);
    k3_wbar<<<B, 256, 0, stream>>>(scp, wbar);
    k4_vagg<<<dim3(8, VS), 256, 0, stream>>>(wbar, pool, vaggp);
    gemm_k5kv<<<dim3(8, SPLITS, 2), 256, 0, stream>>>(Wk, Wv, vaggp, qkvp);
    k6_u<<<B, 256, 0, stream>>>(qkvp, bq, bk, bv, fc, ub);
    gemm_k7<<<dim3(8, SPLITS), 256, 0, stream>>>(Wc, ub, vdp);
    k8_cb<<<B, 256, 0, stream>>>(vdp, bc, Wg, bg, vdiff, cbuf);
    k9_main<<<B * 32, 256, 0, stream>>>(att, Wg, cbuf, vdiff, rs, out);
}